// Round 9
// baseline (247.723 us; speedup 1.0000x reference)
//
#include <hip/hip_runtime.h>
#include <math.h>

typedef __bf16 bf16x8 __attribute__((ext_vector_type(8)));
typedef float f32x4 __attribute__((ext_vector_type(4)));

#define EPSV 1e-5f
#define GLB(p) ((__attribute__((address_space(1))) void*)(p))
#define LDS(p) ((__attribute__((address_space(3))) void*)(p))

__device__ __forceinline__ unsigned fkey(float f) {
  unsigned b = __float_as_uint(f);
  return (b & 0x80000000u) ? ~b : (b | 0x80000000u);
}
__device__ __forceinline__ float funkey(unsigned k) {
  return __uint_as_float((k & 0x80000000u) ? (k & 0x7fffffffu) : ~k);
}

// ---- single-pass norm: block owns p-tile x all C; stats in regs+LDS, then
// apply+store bf16 [N][Ppad][C]. Pad blocks (y>=NWORK) zero the pad rows.
// Block (z=0,y=0) also zeroes ksum[8]. grid (1, 100, 8). ----
__global__ __launch_bounds__(256) void norm_kernel(
    const float* __restrict__ g3, const float* __restrict__ t3,
    __bf16* __restrict__ G3, __bf16* __restrict__ T3,
    const float* __restrict__ g4, const float* __restrict__ t4,
    __bf16* __restrict__ G4, __bf16* __restrict__ T4,
    float* __restrict__ ksum)
{
  if (blockIdx.z == 0 && blockIdx.y == 0 && threadIdx.x < 8)
    ksum[threadIdx.x] = 0.f;
  int lay = blockIdx.z >> 2, n = blockIdx.z & 3;
  const float *gen, *tar; __bf16 *Gh, *Th; int C, P, Ppad, PT, NWORK, NTOT, NG;
  if (lay == 0) { gen = g3; tar = t3; Gh = G3; Th = T3; C = 256; P = 3136; Ppad = 3200; PT = 32; NWORK = 98; NTOT = 100; NG = 8; }
  else          { gen = g4; tar = t4; Gh = G4; Th = T4; C = 512; P = 784;  Ppad = 896;  PT = 16; NWORK = 49; NTOT = 56;  NG = 16; }
  if (blockIdx.y >= (unsigned)NTOT) return;
  int pl, cg;
  if (lay == 0) { pl = threadIdx.x & 31; cg = threadIdx.x >> 5; }
  else          { pl = threadIdx.x & 15; cg = threadIdx.x >> 4; }
  int c0 = cg * 32;

  if (blockIdx.y >= (unsigned)NWORK) {  // zero pad rows
    int p = P + (blockIdx.y - NWORK) * PT + pl;
    if (p < Ppad) {
      __bf16* tp = Th + ((size_t)n * Ppad + p) * C + c0;
      __bf16* gp = Gh + ((size_t)n * Ppad + p) * C + c0;
      bf16x8 z;
      for (int j = 0; j < 8; j++) z[j] = (__bf16)0.f;
      for (int j = 0; j < 32; j += 8) { *(bf16x8*)(tp + j) = z; *(bf16x8*)(gp + j) = z; }
    }
    return;
  }

  int p = blockIdx.y * PT + pl;
  const float* tb = tar + (size_t)n * C * P + (size_t)c0 * P + p;
  const float* gb = gen + (size_t)n * C * P + (size_t)c0 * P + p;
  float tv[32], gv[32];
  float st = 0.f, sst = 0.f, sg = 0.f, ssg = 0.f;
#pragma unroll
  for (int j = 0; j < 32; j++) {
    tv[j] = tb[(size_t)j * P];
    gv[j] = gb[(size_t)j * P];
  }
#pragma unroll
  for (int j = 0; j < 32; j++) {
    st += tv[j]; sst += tv[j] * tv[j];
    sg += gv[j]; ssg += gv[j] * gv[j];
  }
  __shared__ f32x4 red[16][32];
  red[cg][pl] = f32x4{st, sst, sg, ssg};
  __syncthreads();
  for (int h = NG >> 1; h > 0; h >>= 1) {
    if (cg < h) {
      f32x4 a = red[cg][pl], b = red[cg + h][pl];
      red[cg][pl] = f32x4{a[0] + b[0], a[1] + b[1], a[2] + b[2], a[3] + b[3]};
    }
    __syncthreads();
  }
  f32x4 s = red[0][pl];
  float m = s[0] / (float)C;
  float vt = s[1] - s[0] * s[0] / (float)C;
  float vg = s[3] - 2.f * m * s[2] + (float)C * m * m;
  float it = rsqrtf(fmaxf(vt, 1e-30f));
  float ig = rsqrtf(fmaxf(vg, 1e-30f));
  __bf16* tp = Th + ((size_t)n * Ppad + p) * C + c0;
  __bf16* gp = Gh + ((size_t)n * Ppad + p) * C + c0;
#pragma unroll
  for (int j0 = 0; j0 < 32; j0 += 8) {
    bf16x8 to, go;
    for (int j = 0; j < 8; j++) {
      to[j] = (__bf16)((tv[j0 + j] - m) * it);
      go[j] = (__bf16)((gv[j0 + j] - m) * ig);
    }
    *(bf16x8*)(tp + j0) = to;
    *(bf16x8*)(gp + j0) = go;
  }
}

// ---- GEMM: exact r0 config (47.7 us proven): 128x128 tile, BK=64/phase,
// launch_bounds(256,3), 37888-B LDS, 296-B epilogue pitch, nt stores, single
// merged dispatch. NEW: XCD-aware bijective remap (2696 = 8*337 exact):
// HW round-robins blockIdx across 8 XCD-private L2s, so band-neighbors that
// share an A-panel were fetching it into 8 different L2s (FETCH 55 MB vs
// ~21 MB unique). Remap gives each XCD a contiguous band run (panel fits
// its 4 MB L2). Occupancy levers proven neutral; alignment load-bearing
// (64 KiB-multiple shifts only). ----
__global__ __launch_bounds__(256, 3) void gemm_kernel(
    const __bf16* __restrict__ A3, const __bf16* __restrict__ B3,
    __bf16* __restrict__ So3, unsigned* __restrict__ dk3,
    const __bf16* __restrict__ A4, const __bf16* __restrict__ B4,
    __bf16* __restrict__ So4, unsigned* __restrict__ dk4)
{
  // staging: A0 [0,8K) A1 [8K,16K) B0 [16K,24K) B1 [24K,32K)
  // epilogue reuse: 128 rows x 296 B = 37888 B
  __shared__ __attribute__((aligned(16))) char smem[37888];

  int bid = blockIdx.x;
  int id = (bid & 7) * 337 + (bid >> 3);   // XCD-contiguous logical id
  const __bf16 *A, *B; __bf16* S; unsigned* dk;
  int C, Ppad, Qpad, Preal, NT, n, t;
  if (id < 2500) {
    n = id / 625; t = id - n * 625;
    A = A3; B = B3; S = So3; dk = dk3; C = 256; Ppad = 3200; Qpad = 3200; Preal = 3136; NT = 25;
  } else {
    id -= 2500;
    n = id / 49; t = id - n * 49;
    A = A4; B = B4; S = So4; dk = dk4; C = 512; Ppad = 896;  Qpad = 896;  Preal = 784;  NT = 7;
  }
  // band swizzle: bands of 8 p-tiles, q fastest within a band
  int bpb = NT * 8;
  int b = t / bpb, r = t - b * bpb;
  int rem = NT - b * 8;
  int h = rem < 8 ? rem : 8;
  int pt = b * 8 + r % h, qt = r / h;
  int p0 = pt * 128, q0 = qt * 128;

  int tid = threadIdx.x;
  int w = tid >> 6, lane = tid & 63;
  int lm = lane & 15, lq = lane >> 4;
  int wrow = (w >> 1) * 64, wcol = (w & 1) * 64;

  // staging: thread tid -> row tid>>2 (and +64), chunk-slot tid&3 (16B);
  // slot s of row r holds global chunk s ^ ((r>>1)&3) (proven 0-conflict).
  int srow = tid >> 2;
  int scol = ((tid & 3) ^ ((tid >> 3) & 3)) * 8;
  const __bf16* gA = A + ((size_t)n * Ppad + p0 + srow) * C + scol;
  const __bf16* gB = B + ((size_t)n * Qpad + q0 + srow) * C + scol;
  size_t rowoff = (size_t)64 * C;

  // fragment read: row R + chunk lq -> slot lq ^ ((lm>>1)&3)
  int sl = lq ^ ((lm >> 1) & 3);
  int aoff = (wrow + lm) * 64 + sl * 16;   // + i*1024 per i-tile
  int boff = (wcol + lm) * 64 + sl * 16;

  f32x4 acc[4][4];
  for (int i = 0; i < 4; i++)
    for (int j = 0; j < 4; j++)
      acc[i][j] = f32x4{0.f, 0.f, 0.f, 0.f};

  for (int k0 = 0; k0 < C; k0 += 64) {
    __syncthreads();
#pragma unroll
    for (int sub = 0; sub < 2; sub++) {
      int kk = k0 + sub * 32;
      char* a = smem + sub * 8192 + w * 1024;
      char* bb = smem + 16384 + sub * 8192 + w * 1024;
      __builtin_amdgcn_global_load_lds(GLB(gA + kk), LDS(a), 16, 0, 0);
      __builtin_amdgcn_global_load_lds(GLB(gA + rowoff + kk), LDS(a + 4096), 16, 0, 0);
      __builtin_amdgcn_global_load_lds(GLB(gB + kk), LDS(bb), 16, 0, 0);
      __builtin_amdgcn_global_load_lds(GLB(gB + rowoff + kk), LDS(bb + 4096), 16, 0, 0);
    }
    __syncthreads();
#pragma unroll
    for (int sub = 0; sub < 2; sub++) {
      const char* ab = smem + sub * 8192;
      const char* bb = smem + 16384 + sub * 8192;
      bf16x8 af[4], bf[4];
      for (int i = 0; i < 4; i++) af[i] = *(const bf16x8*)(ab + aoff + i * 1024);
      for (int j = 0; j < 4; j++) bf[j] = *(const bf16x8*)(bb + boff + j * 1024);
      for (int i = 0; i < 4; i++)
        for (int j = 0; j < 4; j++)
          acc[i][j] = __builtin_amdgcn_mfma_f32_16x16x32_bf16(af[i], bf[j], acc[i][j], 0, 0, 0);
    }
  }

  // colmax from registers (D: row = lq*4+ri, col = lm within 16x16 sub-tile)
  float cm[4] = {-INFINITY, -INFINITY, -INFINITY, -INFINITY};
  for (int i = 0; i < 4; i++)
    for (int j = 0; j < 4; j++)
      for (int ri = 0; ri < 4; ri++) {
        int pr = p0 + wrow + i * 16 + lq * 4 + ri;
        if (pr < Preal) cm[j] = fmaxf(cm[j], (float)(__bf16)acc[i][j][ri]);
      }

  // epilogue: bounce through LDS (296-B pitch: banks = lq*8 + lm/2, conflict-
  // free), then fully-coalesced non-temporal bf16x8 row stores.
  __syncthreads();
  for (int i = 0; i < 4; i++) {
    for (int j = 0; j < 4; j++) {
      int row = wrow + i * 16 + lq * 4;
      int col = wcol + j * 16 + lm;
      for (int ri = 0; ri < 4; ri++)
        *(__bf16*)(smem + (row + ri) * 296 + col * 2) = (__bf16)acc[i][j][ri];
    }
  }
  __syncthreads();
  __bf16* Sb = S + (size_t)n * Ppad * Qpad;
  int rr = tid >> 4, cc8 = (tid & 15) * 8;
  for (int r8 = 0; r8 < 8; r8++) {
    int row = r8 * 16 + rr;
    bf16x8 v = *(const bf16x8*)(smem + row * 296 + cc8 * 2);
    __builtin_nontemporal_store(v, (bf16x8*)(Sb + (size_t)(p0 + row) * Qpad + q0 + cc8));
  }

  for (int j = 0; j < 4; j++) {
    float v = cm[j];
    v = fmaxf(v, __shfl_xor(v, 16, 64));
    v = fmaxf(v, __shfl_xor(v, 32, 64));
    if (lq == 0 && v > -INFINITY) {
      int qc = q0 + wcol + j * 16 + lm;
      atomicMax(&dk[(size_t)n * Qpad + qc], fkey(v));
    }
  }
}

// ---- z: block = q-tile(2048) x p-slab(32/16); accumulate slab in regs then
// ONE fp32 atomicAdd per (q) into Z (<=98 adds/address, spread in time).
// Replaces the Zp slab buffer (5.7 MB write + read) and reduce's sum loop.
// exp2f-folded coefficients (exp2f -> v_exp_f32 directly; __exp2f does not
// exist as a device builtin — r8 compile fail). exact 1D grid: 980 ----
__global__ __launch_bounds__(256) void z_kernel(
    const __bf16* __restrict__ S3, const unsigned* __restrict__ dk3, float* __restrict__ Z3,
    const __bf16* __restrict__ S4, const unsigned* __restrict__ dk4, float* __restrict__ Z4)
{
  int id = blockIdx.x;
  const __bf16* S; const unsigned* dk; float* Z;
  int Ppad, Qreal, Qpad, SLAB, n, qx, sy;
  if (id < 784) {
    n = id / 196; int r = id - n * 196; sy = r >> 1; qx = r & 1;
    S = S3; dk = dk3; Z = Z3; Ppad = 3200; Qreal = 3136; Qpad = 3200; SLAB = 32;
  } else {
    id -= 784;
    n = id / 49; sy = id - n * 49; qx = 0;
    S = S4; dk = dk4; Z = Z4; Ppad = 896;  Qreal = 784;  Qpad = 896;  SLAB = 16;
  }
  int q = (qx * 256 + threadIdx.x) * 8;
  if (q >= Qreal) return;
  float idv2[8], nid2[8];
  const unsigned* dkp = dk + (size_t)n * Qpad + q;
#pragma unroll
  for (int j = 0; j < 8; j++) {
    float mx = funkey(dkp[j]);
    float d = 0.5f * (1.f - mx) + EPSV;
    float iv = 1.4426950408889634f / d;   // log2(e)/d
    idv2[j] = iv;
    nid2[j] = -iv;
  }
  int p0 = sy * SLAB;
  const __bf16* Sp = S + (size_t)n * Ppad * Qpad + q;
  float acc[8] = {0.f, 0.f, 0.f, 0.f, 0.f, 0.f, 0.f, 0.f};
  for (int pb = 0; pb < SLAB; pb += 8) {
    bf16x8 sv[8];
#pragma unroll
    for (int r = 0; r < 8; r++)
      sv[r] = *(const bf16x8*)(Sp + (size_t)(p0 + pb + r) * Qpad);
#pragma unroll
    for (int r = 0; r < 8; r++)
      for (int j = 0; j < 8; j++)
        acc[j] += exp2f(fmaf((float)sv[r][j], idv2[j], nid2[j]));
  }
  float* zp = Z + (size_t)n * Qpad + q;
#pragma unroll
  for (int j = 0; j < 8; j++) atomicAdd(zp + j, acc[j]);
}

// ---- reduce: invd[q] = 1/d ; c[q] = -log(Z[q]) - invd ---- grid (13,8)
__global__ __launch_bounds__(256) void reduce_kernel(
    const float* __restrict__ Z3, const unsigned* __restrict__ dk3,
    float* __restrict__ invd3, float* __restrict__ c3,
    const float* __restrict__ Z4, const unsigned* __restrict__ dk4,
    float* __restrict__ invd4, float* __restrict__ c4)
{
  int lay = blockIdx.y >> 2, n = blockIdx.y & 3;
  const float* Z; const unsigned* dk; float *invd, *c; int Qreal, Qpad;
  if (lay == 0) { Z = Z3; dk = dk3; invd = invd3; c = c3; Qreal = 3136; Qpad = 3200; }
  else          { Z = Z4; dk = dk4; invd = invd4; c = c4; Qreal = 784;  Qpad = 896;  }
  int q = blockIdx.x * 256 + threadIdx.x;
  if (q >= Qreal) return;
  float s = Z[(size_t)n * Qpad + q];
  float mx = funkey(dk[(size_t)n * Qpad + q]);
  float d = 0.5f * (1.f - mx) + EPSV;
  float idv = 1.f / d;
  invd[(size_t)n * Qpad + q] = idv;
  c[(size_t)n * Qpad + q] = -logf(s) - idv;
}

// ---- rowmax: per-block max_q (S*invd + c) over ROWS rows, exp'd + summed,
// one atomicAdd into ksum[lay*4+n]. ROWS=32 (L3) / 16 (L4): 588 blocks. ----
template<int ROWS>
__device__ __forceinline__ float rowmax_partial(
    const __bf16* __restrict__ Sp, const float* __restrict__ idp,
    const float* __restrict__ cp, int nq8, int Qpad)
{
  float m[ROWS];
#pragma unroll
  for (int r = 0; r < ROWS; r++) m[r] = -INFINITY;
  for (int i = threadIdx.x; i < nq8; i += 256) {
    f32x4 i0 = *(const f32x4*)(idp + (size_t)i * 8);
    f32x4 i1 = *(const f32x4*)(idp + (size_t)i * 8 + 4);
    f32x4 c0 = *(const f32x4*)(cp + (size_t)i * 8);
    f32x4 c1 = *(const f32x4*)(cp + (size_t)i * 8 + 4);
#pragma unroll
    for (int r = 0; r < ROWS; r++) {
      bf16x8 sv = *(const bf16x8*)(Sp + (size_t)r * Qpad + (size_t)i * 8);
#pragma unroll
      for (int j = 0; j < 4; j++)
        m[r] = fmaxf(m[r], fmaf((float)sv[j], i0[j], c0[j]));
#pragma unroll
      for (int j = 0; j < 4; j++)
        m[r] = fmaxf(m[r], fmaf((float)sv[j + 4], i1[j], c1[j]));
    }
  }
#pragma unroll
  for (int r = 0; r < ROWS; r++)
    for (int off = 32; off > 0; off >>= 1)
      m[r] = fmaxf(m[r], __shfl_xor(m[r], off, 64));
  __shared__ float red[4][ROWS];
  int w = threadIdx.x >> 6;
  if ((threadIdx.x & 63) == 0)
#pragma unroll
    for (int r = 0; r < ROWS; r++) red[w][r] = m[r];
  __syncthreads();
  float e = 0.f;
  if (threadIdx.x < ROWS) {
    int r = threadIdx.x;
    float mr = fmaxf(fmaxf(red[0][r], red[1][r]), fmaxf(red[2][r], red[3][r]));
    e = __expf(mr);
  }
  if (threadIdx.x < 64) {
#pragma unroll
    for (int off = 1; off < ROWS; off <<= 1)
      e += __shfl_xor(e, off, 64);
  }
  return e;  // valid in lane 0
}

__global__ __launch_bounds__(256) void rowmax_kernel(
    const __bf16* __restrict__ S3, const float* __restrict__ invd3,
    const float* __restrict__ c3,
    const __bf16* __restrict__ S4, const float* __restrict__ invd4,
    const float* __restrict__ c4, float* __restrict__ ksum)
{
  int id = blockIdx.x;
  if (id < 392) {
    int n = id / 98, blk = id - n * 98;
    const __bf16* Sp = S3 + ((size_t)n * 3200 + blk * 32) * 3200;
    float e = rowmax_partial<32>(Sp, invd3 + (size_t)n * 3200,
                                 c3 + (size_t)n * 3200, 392, 3200);
    if (threadIdx.x == 0) atomicAdd(&ksum[n], e);
  } else {
    id -= 392;
    int n = id / 49, blk = id - n * 49;
    const __bf16* Sp = S4 + ((size_t)n * 896 + blk * 16) * 896;
    float e = rowmax_partial<16>(Sp, invd4 + (size_t)n * 896,
                                 c4 + (size_t)n * 896, 98, 896);
    if (threadIdx.x == 0) atomicAdd(&ksum[4 + n], e);
  }
}

// loss = 0.5 * sum_n -log(ksum3/P3) + 1.0 * sum_n -log(ksum4/P4)
__global__ void final_kernel(const float* __restrict__ ksum, float* __restrict__ out)
{
  if (threadIdx.x == 0) {
    float lp3 = logf(3136.f), lp4 = logf(784.f);
    float total = 0.f;
    for (int n = 0; n < 4; n++) total += 0.5f * (lp3 - logf(ksum[n]));
    for (int n = 0; n < 4; n++) total += 1.0f * (lp4 - logf(ksum[4 + n]));
    out[0] = total;
  }
}

extern "C" void kernel_launch(void* const* d_in, const int* in_sizes, int n_in,
                              void* d_out, int out_size, void* d_ws, size_t ws_size,
                              hipStream_t stream)
{
  const float* gen3 = (const float*)d_in[0];
  const float* tar3 = (const float*)d_in[1];
  const float* gen4 = (const float*)d_in[2];
  const float* tar4 = (const float*)d_in[3];

  char* ws = (char*)d_ws;
  size_t off = 0;
  auto take = [&](size_t bytes) { char* p = ws + off; off += bytes; return p; };

  // ---- zeroed region. Z3+Z4 added = exactly 65536 B, so the big buffers
  // shift by one 64-KiB step: alignment class unchanged (the r1/r2 +28%
  // GEMM regression was a 32-B shift; 64-B+ multiples are safe). ----
  unsigned* divkey3 = (unsigned*)take(51200);   // 4*3200*4
  unsigned* divkey4 = (unsigned*)take(14336);   // 4*896*4
  float*    Z3      = (float*)   take(51200);   // 4*3200*4 (atomic sums)
  float*    Z4      = (float*)   take(14336);   // 4*896*4
  size_t zero_bytes = off;                      // = 131072
  __bf16* That3 = (__bf16*)take(6553600);       // 4*3200*256*2   @ 131072
  __bf16* Ghat3 = (__bf16*)take(6553600);
  __bf16* That4 = (__bf16*)take(3670016);       // 4*896*512*2
  __bf16* Ghat4 = (__bf16*)take(3670016);
  __bf16* S3    = (__bf16*)take(81920000);      // 4*3200*3200*2
  __bf16* S4    = (__bf16*)take(6422528);       // 4*896*896*2
  float* invd3  = (float*)take(51200);
  float* c3     = (float*)take(51200);
  float* ksum   = (float*)take(51200);          // first 32 B used
  float* invd4  = (float*)take(14336);
  float* c4     = (float*)take(14336);

  hipMemsetAsync(divkey3, 0, zero_bytes, stream);

  norm_kernel<<<dim3(1, 100, 8), 256, 0, stream>>>(gen3, tar3, Ghat3, That3,
                                                   gen4, tar4, Ghat4, That4, ksum);
  gemm_kernel<<<2696, 256, 0, stream>>>(That3, Ghat3, S3, divkey3,
                                        That4, Ghat4, S4, divkey4);
  z_kernel<<<980, 256, 0, stream>>>(S3, divkey3, Z3,
                                    S4, divkey4, Z4);
  reduce_kernel<<<dim3(13, 8), 256, 0, stream>>>(Z3, divkey3, invd3, c3,
                                                 Z4, divkey4, invd4, c4);
  rowmax_kernel<<<588, 256, 0, stream>>>(S3, invd3, c3,
                                         S4, invd4, c4, ksum);
  final_kernel<<<1, 64, 0, stream>>>(ksum, (float*)d_out);
}

// Round 10
// 201.630 us; speedup vs baseline: 1.2286x; 1.2286x over previous
//
#include <hip/hip_runtime.h>
#include <math.h>

typedef __bf16 bf16x8 __attribute__((ext_vector_type(8)));
typedef float f32x4 __attribute__((ext_vector_type(4)));

#define EPSV 1e-5f
#define GLB(p) ((__attribute__((address_space(1))) void*)(p))
#define LDS(p) ((__attribute__((address_space(3))) void*)(p))

__device__ __forceinline__ unsigned fkey(float f) {
  unsigned b = __float_as_uint(f);
  return (b & 0x80000000u) ? ~b : (b | 0x80000000u);
}
__device__ __forceinline__ float funkey(unsigned k) {
  return __uint_as_float((k & 0x80000000u) ? (k & 0x7fffffffu) : ~k);
}

// ---- single-pass norm: block owns p-tile x all C; stats in regs+LDS, then
// apply+store bf16 [N][Ppad][C]. Pad blocks (y>=NWORK) zero the pad rows.
// Block (z=0,y=0) also zeroes ksum[8]. grid (1, 100, 8). ----
__global__ __launch_bounds__(256) void norm_kernel(
    const float* __restrict__ g3, const float* __restrict__ t3,
    __bf16* __restrict__ G3, __bf16* __restrict__ T3,
    const float* __restrict__ g4, const float* __restrict__ t4,
    __bf16* __restrict__ G4, __bf16* __restrict__ T4,
    float* __restrict__ ksum)
{
  if (blockIdx.z == 0 && blockIdx.y == 0 && threadIdx.x < 8)
    ksum[threadIdx.x] = 0.f;
  int lay = blockIdx.z >> 2, n = blockIdx.z & 3;
  const float *gen, *tar; __bf16 *Gh, *Th; int C, P, Ppad, PT, NWORK, NTOT, NG;
  if (lay == 0) { gen = g3; tar = t3; Gh = G3; Th = T3; C = 256; P = 3136; Ppad = 3200; PT = 32; NWORK = 98; NTOT = 100; NG = 8; }
  else          { gen = g4; tar = t4; Gh = G4; Th = T4; C = 512; P = 784;  Ppad = 896;  PT = 16; NWORK = 49; NTOT = 56;  NG = 16; }
  if (blockIdx.y >= (unsigned)NTOT) return;
  int pl, cg;
  if (lay == 0) { pl = threadIdx.x & 31; cg = threadIdx.x >> 5; }
  else          { pl = threadIdx.x & 15; cg = threadIdx.x >> 4; }
  int c0 = cg * 32;

  if (blockIdx.y >= (unsigned)NWORK) {  // zero pad rows
    int p = P + (blockIdx.y - NWORK) * PT + pl;
    if (p < Ppad) {
      __bf16* tp = Th + ((size_t)n * Ppad + p) * C + c0;
      __bf16* gp = Gh + ((size_t)n * Ppad + p) * C + c0;
      bf16x8 z;
      for (int j = 0; j < 8; j++) z[j] = (__bf16)0.f;
      for (int j = 0; j < 32; j += 8) { *(bf16x8*)(tp + j) = z; *(bf16x8*)(gp + j) = z; }
    }
    return;
  }

  int p = blockIdx.y * PT + pl;
  const float* tb = tar + (size_t)n * C * P + (size_t)c0 * P + p;
  const float* gb = gen + (size_t)n * C * P + (size_t)c0 * P + p;
  float tv[32], gv[32];
  float st = 0.f, sst = 0.f, sg = 0.f, ssg = 0.f;
#pragma unroll
  for (int j = 0; j < 32; j++) {
    tv[j] = tb[(size_t)j * P];
    gv[j] = gb[(size_t)j * P];
  }
#pragma unroll
  for (int j = 0; j < 32; j++) {
    st += tv[j]; sst += tv[j] * tv[j];
    sg += gv[j]; ssg += gv[j] * gv[j];
  }
  __shared__ f32x4 red[16][32];
  red[cg][pl] = f32x4{st, sst, sg, ssg};
  __syncthreads();
  for (int h = NG >> 1; h > 0; h >>= 1) {
    if (cg < h) {
      f32x4 a = red[cg][pl], b = red[cg + h][pl];
      red[cg][pl] = f32x4{a[0] + b[0], a[1] + b[1], a[2] + b[2], a[3] + b[3]};
    }
    __syncthreads();
  }
  f32x4 s = red[0][pl];
  float m = s[0] / (float)C;
  float vt = s[1] - s[0] * s[0] / (float)C;
  float vg = s[3] - 2.f * m * s[2] + (float)C * m * m;
  float it = rsqrtf(fmaxf(vt, 1e-30f));
  float ig = rsqrtf(fmaxf(vg, 1e-30f));
  __bf16* tp = Th + ((size_t)n * Ppad + p) * C + c0;
  __bf16* gp = Gh + ((size_t)n * Ppad + p) * C + c0;
#pragma unroll
  for (int j0 = 0; j0 < 32; j0 += 8) {
    bf16x8 to, go;
    for (int j = 0; j < 8; j++) {
      to[j] = (__bf16)((tv[j0 + j] - m) * it);
      go[j] = (__bf16)((gv[j0 + j] - m) * ig);
    }
    *(bf16x8*)(tp + j0) = to;
    *(bf16x8*)(gp + j0) = go;
  }
}

// ---- GEMM: exact r0 config (47.7 us proven) + XCD-aware bijective remap
// (2696 = 8*337 exact): HW round-robins blockIdx across 8 XCD-private L2s,
// so band-neighbors sharing an A-panel were fetching it into 8 different
// L2s. Remap gives each XCD a contiguous band run. UNVALIDATED as of r10
// (r9's z regression hid gemm from top-5) — this round is its clean A/B vs
// r7's 49.3 us / 54.9 MB FETCH. Occupancy levers proven neutral; alignment
// load-bearing (64 KiB-multiple shifts only). ----
__global__ __launch_bounds__(256, 3) void gemm_kernel(
    const __bf16* __restrict__ A3, const __bf16* __restrict__ B3,
    __bf16* __restrict__ So3, unsigned* __restrict__ dk3,
    const __bf16* __restrict__ A4, const __bf16* __restrict__ B4,
    __bf16* __restrict__ So4, unsigned* __restrict__ dk4)
{
  // staging: A0 [0,8K) A1 [8K,16K) B0 [16K,24K) B1 [24K,32K)
  // epilogue reuse: 128 rows x 296 B = 37888 B
  __shared__ __attribute__((aligned(16))) char smem[37888];

  int bid = blockIdx.x;
  int id = (bid & 7) * 337 + (bid >> 3);   // XCD-contiguous logical id
  const __bf16 *A, *B; __bf16* S; unsigned* dk;
  int C, Ppad, Qpad, Preal, NT, n, t;
  if (id < 2500) {
    n = id / 625; t = id - n * 625;
    A = A3; B = B3; S = So3; dk = dk3; C = 256; Ppad = 3200; Qpad = 3200; Preal = 3136; NT = 25;
  } else {
    id -= 2500;
    n = id / 49; t = id - n * 49;
    A = A4; B = B4; S = So4; dk = dk4; C = 512; Ppad = 896;  Qpad = 896;  Preal = 784;  NT = 7;
  }
  // band swizzle: bands of 8 p-tiles, q fastest within a band
  int bpb = NT * 8;
  int b = t / bpb, r = t - b * bpb;
  int rem = NT - b * 8;
  int h = rem < 8 ? rem : 8;
  int pt = b * 8 + r % h, qt = r / h;
  int p0 = pt * 128, q0 = qt * 128;

  int tid = threadIdx.x;
  int w = tid >> 6, lane = tid & 63;
  int lm = lane & 15, lq = lane >> 4;
  int wrow = (w >> 1) * 64, wcol = (w & 1) * 64;

  // staging: thread tid -> row tid>>2 (and +64), chunk-slot tid&3 (16B);
  // slot s of row r holds global chunk s ^ ((r>>1)&3) (proven 0-conflict).
  int srow = tid >> 2;
  int scol = ((tid & 3) ^ ((tid >> 3) & 3)) * 8;
  const __bf16* gA = A + ((size_t)n * Ppad + p0 + srow) * C + scol;
  const __bf16* gB = B + ((size_t)n * Qpad + q0 + srow) * C + scol;
  size_t rowoff = (size_t)64 * C;

  // fragment read: row R + chunk lq -> slot lq ^ ((lm>>1)&3)
  int sl = lq ^ ((lm >> 1) & 3);
  int aoff = (wrow + lm) * 64 + sl * 16;   // + i*1024 per i-tile
  int boff = (wcol + lm) * 64 + sl * 16;

  f32x4 acc[4][4];
  for (int i = 0; i < 4; i++)
    for (int j = 0; j < 4; j++)
      acc[i][j] = f32x4{0.f, 0.f, 0.f, 0.f};

  for (int k0 = 0; k0 < C; k0 += 64) {
    __syncthreads();
#pragma unroll
    for (int sub = 0; sub < 2; sub++) {
      int kk = k0 + sub * 32;
      char* a = smem + sub * 8192 + w * 1024;
      char* bb = smem + 16384 + sub * 8192 + w * 1024;
      __builtin_amdgcn_global_load_lds(GLB(gA + kk), LDS(a), 16, 0, 0);
      __builtin_amdgcn_global_load_lds(GLB(gA + rowoff + kk), LDS(a + 4096), 16, 0, 0);
      __builtin_amdgcn_global_load_lds(GLB(gB + kk), LDS(bb), 16, 0, 0);
      __builtin_amdgcn_global_load_lds(GLB(gB + rowoff + kk), LDS(bb + 4096), 16, 0, 0);
    }
    __syncthreads();
#pragma unroll
    for (int sub = 0; sub < 2; sub++) {
      const char* ab = smem + sub * 8192;
      const char* bb = smem + 16384 + sub * 8192;
      bf16x8 af[4], bf[4];
      for (int i = 0; i < 4; i++) af[i] = *(const bf16x8*)(ab + aoff + i * 1024);
      for (int j = 0; j < 4; j++) bf[j] = *(const bf16x8*)(bb + boff + j * 1024);
      for (int i = 0; i < 4; i++)
        for (int j = 0; j < 4; j++)
          acc[i][j] = __builtin_amdgcn_mfma_f32_16x16x32_bf16(af[i], bf[j], acc[i][j], 0, 0, 0);
    }
  }

  // colmax from registers (D: row = lq*4+ri, col = lm within 16x16 sub-tile)
  float cm[4] = {-INFINITY, -INFINITY, -INFINITY, -INFINITY};
  for (int i = 0; i < 4; i++)
    for (int j = 0; j < 4; j++)
      for (int ri = 0; ri < 4; ri++) {
        int pr = p0 + wrow + i * 16 + lq * 4 + ri;
        if (pr < Preal) cm[j] = fmaxf(cm[j], (float)(__bf16)acc[i][j][ri]);
      }

  // epilogue: bounce through LDS (296-B pitch: banks = lq*8 + lm/2, conflict-
  // free), then fully-coalesced non-temporal bf16x8 row stores.
  __syncthreads();
  for (int i = 0; i < 4; i++) {
    for (int j = 0; j < 4; j++) {
      int row = wrow + i * 16 + lq * 4;
      int col = wcol + j * 16 + lm;
      for (int ri = 0; ri < 4; ri++)
        *(__bf16*)(smem + (row + ri) * 296 + col * 2) = (__bf16)acc[i][j][ri];
    }
  }
  __syncthreads();
  __bf16* Sb = S + (size_t)n * Ppad * Qpad;
  int rr = tid >> 4, cc8 = (tid & 15) * 8;
  for (int r8 = 0; r8 < 8; r8++) {
    int row = r8 * 16 + rr;
    bf16x8 v = *(const bf16x8*)(smem + row * 296 + cc8 * 2);
    __builtin_nontemporal_store(v, (bf16x8*)(Sb + (size_t)(p0 + row) * Qpad + q0 + cc8));
  }

  for (int j = 0; j < 4; j++) {
    float v = cm[j];
    v = fmaxf(v, __shfl_xor(v, 16, 64));
    v = fmaxf(v, __shfl_xor(v, 32, 64));
    if (lq == 0 && v > -INFINITY) {
      int qc = q0 + wcol + j * 16 + lm;
      atomicMax(&dk[(size_t)n * Qpad + qc], fkey(v));
    }
  }
}

// ---- z partials: block = q-tile(2048) x p-slab(32/16); NO atomics
// (r9's atomicAdd-to-Z design: 43 MB HBM write, z 81 us — cross-XCD fp32
// atomics resolve at the fabric, each one an HBM transaction. Slab partials
// + reduce is 3x faster). exp2f-folded coefficients kept (same math, one
// less mul). exact 1D grid: 980 blocks ----
__global__ __launch_bounds__(256) void z_kernel(
    const __bf16* __restrict__ S3, const unsigned* __restrict__ dk3, float* __restrict__ Zp3,
    const __bf16* __restrict__ S4, const unsigned* __restrict__ dk4, float* __restrict__ Zp4)
{
  int id = blockIdx.x;
  const __bf16* S; const unsigned* dk; float* Zp;
  int Ppad, Qreal, Qpad, NSL, SLAB, n, qx, sy;
  if (id < 784) {
    n = id / 196; int r = id - n * 196; sy = r >> 1; qx = r & 1;
    S = S3; dk = dk3; Zp = Zp3; Ppad = 3200; Qreal = 3136; Qpad = 3200; NSL = 98; SLAB = 32;
  } else {
    id -= 784;
    n = id / 49; sy = id - n * 49; qx = 0;
    S = S4; dk = dk4; Zp = Zp4; Ppad = 896;  Qreal = 784;  Qpad = 896;  NSL = 49; SLAB = 16;
  }
  int q = (qx * 256 + threadIdx.x) * 8;
  if (q >= Qreal) return;
  float idv2[8], nid2[8];
  const unsigned* dkp = dk + (size_t)n * Qpad + q;
#pragma unroll
  for (int j = 0; j < 8; j++) {
    float mx = funkey(dkp[j]);
    float d = 0.5f * (1.f - mx) + EPSV;
    float iv = 1.4426950408889634f / d;   // log2(e)/d
    idv2[j] = iv;
    nid2[j] = -iv;
  }
  int p0 = sy * SLAB;
  const __bf16* Sp = S + (size_t)n * Ppad * Qpad + q;
  float acc[8] = {0.f, 0.f, 0.f, 0.f, 0.f, 0.f, 0.f, 0.f};
  for (int pb = 0; pb < SLAB; pb += 8) {
    bf16x8 sv[8];
#pragma unroll
    for (int r = 0; r < 8; r++)
      sv[r] = *(const bf16x8*)(Sp + (size_t)(p0 + pb + r) * Qpad);
#pragma unroll
    for (int r = 0; r < 8; r++)
      for (int j = 0; j < 8; j++)
        acc[j] += exp2f(fmaf((float)sv[r][j], idv2[j], nid2[j]));
  }
  float* zp = Zp + ((size_t)n * NSL + sy) * Qpad + q;
  *(f32x4*)zp = f32x4{acc[0], acc[1], acc[2], acc[3]};
  *(f32x4*)(zp + 4) = f32x4{acc[4], acc[5], acc[6], acc[7]};
}

// ---- reduce: Z[q] = sum_slab Zp ; invd[q] ; c[q] = -log(Z)-invd ---- grid (13,8)
__global__ __launch_bounds__(256) void reduce_kernel(
    const float* __restrict__ Zp3, const unsigned* __restrict__ dk3,
    float* __restrict__ invd3, float* __restrict__ c3,
    const float* __restrict__ Zp4, const unsigned* __restrict__ dk4,
    float* __restrict__ invd4, float* __restrict__ c4)
{
  int lay = blockIdx.y >> 2, n = blockIdx.y & 3;
  const float* Zp; const unsigned* dk; float *invd, *c; int Qreal, Qpad, NSL;
  if (lay == 0) { Zp = Zp3; dk = dk3; invd = invd3; c = c3; Qreal = 3136; Qpad = 3200; NSL = 98; }
  else          { Zp = Zp4; dk = dk4; invd = invd4; c = c4; Qreal = 784;  Qpad = 896;  NSL = 49; }
  int q = blockIdx.x * 256 + threadIdx.x;
  if (q >= Qreal) return;
  float s0 = 0.f, s1 = 0.f, s2 = 0.f, s3 = 0.f;
  int sl = 0;
  for (; sl + 4 <= NSL; sl += 4) {
    s0 += Zp[((size_t)n * NSL + sl) * Qpad + q];
    s1 += Zp[((size_t)n * NSL + sl + 1) * Qpad + q];
    s2 += Zp[((size_t)n * NSL + sl + 2) * Qpad + q];
    s3 += Zp[((size_t)n * NSL + sl + 3) * Qpad + q];
  }
  for (; sl < NSL; sl++) s0 += Zp[((size_t)n * NSL + sl) * Qpad + q];
  float s = (s0 + s1) + (s2 + s3);
  float mx = funkey(dk[(size_t)n * Qpad + q]);
  float d = 0.5f * (1.f - mx) + EPSV;
  float idv = 1.f / d;
  invd[(size_t)n * Qpad + q] = idv;
  c[(size_t)n * Qpad + q] = -logf(s) - idv;
}

// ---- rowmax: per-block max_q (S*invd + c) over ROWS rows, exp'd + summed,
// one atomicAdd into ksum[lay*4+n]. ROWS=32 (L3) / 16 (L4): 588 blocks. ----
template<int ROWS>
__device__ __forceinline__ float rowmax_partial(
    const __bf16* __restrict__ Sp, const float* __restrict__ idp,
    const float* __restrict__ cp, int nq8, int Qpad)
{
  float m[ROWS];
#pragma unroll
  for (int r = 0; r < ROWS; r++) m[r] = -INFINITY;
  for (int i = threadIdx.x; i < nq8; i += 256) {
    f32x4 i0 = *(const f32x4*)(idp + (size_t)i * 8);
    f32x4 i1 = *(const f32x4*)(idp + (size_t)i * 8 + 4);
    f32x4 c0 = *(const f32x4*)(cp + (size_t)i * 8);
    f32x4 c1 = *(const f32x4*)(cp + (size_t)i * 8 + 4);
#pragma unroll
    for (int r = 0; r < ROWS; r++) {
      bf16x8 sv = *(const bf16x8*)(Sp + (size_t)r * Qpad + (size_t)i * 8);
#pragma unroll
      for (int j = 0; j < 4; j++)
        m[r] = fmaxf(m[r], fmaf((float)sv[j], i0[j], c0[j]));
#pragma unroll
      for (int j = 0; j < 4; j++)
        m[r] = fmaxf(m[r], fmaf((float)sv[j + 4], i1[j], c1[j]));
    }
  }
#pragma unroll
  for (int r = 0; r < ROWS; r++)
    for (int off = 32; off > 0; off >>= 1)
      m[r] = fmaxf(m[r], __shfl_xor(m[r], off, 64));
  __shared__ float red[4][ROWS];
  int w = threadIdx.x >> 6;
  if ((threadIdx.x & 63) == 0)
#pragma unroll
    for (int r = 0; r < ROWS; r++) red[w][r] = m[r];
  __syncthreads();
  float e = 0.f;
  if (threadIdx.x < ROWS) {
    int r = threadIdx.x;
    float mr = fmaxf(fmaxf(red[0][r], red[1][r]), fmaxf(red[2][r], red[3][r]));
    e = __expf(mr);
  }
  if (threadIdx.x < 64) {
#pragma unroll
    for (int off = 1; off < ROWS; off <<= 1)
      e += __shfl_xor(e, off, 64);
  }
  return e;  // valid in lane 0
}

__global__ __launch_bounds__(256) void rowmax_kernel(
    const __bf16* __restrict__ S3, const float* __restrict__ invd3,
    const float* __restrict__ c3,
    const __bf16* __restrict__ S4, const float* __restrict__ invd4,
    const float* __restrict__ c4, float* __restrict__ ksum)
{
  int id = blockIdx.x;
  if (id < 392) {
    int n = id / 98, blk = id - n * 98;
    const __bf16* Sp = S3 + ((size_t)n * 3200 + blk * 32) * 3200;
    float e = rowmax_partial<32>(Sp, invd3 + (size_t)n * 3200,
                                 c3 + (size_t)n * 3200, 392, 3200);
    if (threadIdx.x == 0) atomicAdd(&ksum[n], e);
  } else {
    id -= 392;
    int n = id / 49, blk = id - n * 49;
    const __bf16* Sp = S4 + ((size_t)n * 896 + blk * 16) * 896;
    float e = rowmax_partial<16>(Sp, invd4 + (size_t)n * 896,
                                 c4 + (size_t)n * 896, 98, 896);
    if (threadIdx.x == 0) atomicAdd(&ksum[4 + n], e);
  }
}

// loss = 0.5 * sum_n -log(ksum3/P3) + 1.0 * sum_n -log(ksum4/P4)
__global__ void final_kernel(const float* __restrict__ ksum, float* __restrict__ out)
{
  if (threadIdx.x == 0) {
    float lp3 = logf(3136.f), lp4 = logf(784.f);
    float total = 0.f;
    for (int n = 0; n < 4; n++) total += 0.5f * (lp3 - logf(ksum[n]));
    for (int n = 0; n < 4; n++) total += 1.0f * (lp4 - logf(ksum[4 + n]));
    out[0] = total;
  }
}

extern "C" void kernel_launch(void* const* d_in, const int* in_sizes, int n_in,
                              void* d_out, int out_size, void* d_ws, size_t ws_size,
                              hipStream_t stream)
{
  const float* gen3 = (const float*)d_in[0];
  const float* tar3 = (const float*)d_in[1];
  const float* gen4 = (const float*)d_in[2];
  const float* tar4 = (const float*)d_in[3];

  char* ws = (char*)d_ws;
  size_t off = 0;
  auto take = [&](size_t bytes) { char* p = ws + off; off += bytes; return p; };

  // ---- workspace layout: byte-identical to r7's proven 195.3-us layout.
  // DO NOT insert allocations before the big buffers (32-B shift = +28%
  // GEMM, r1/r2). ----
  unsigned* divkey3 = (unsigned*)take(51200);   // 4*3200*4
  unsigned* divkey4 = (unsigned*)take(14336);   // 4*896*4
  size_t zero_bytes = off;                      // = 65536
  __bf16* That3 = (__bf16*)take(6553600);       // 4*3200*256*2   @ 65536
  __bf16* Ghat3 = (__bf16*)take(6553600);
  __bf16* That4 = (__bf16*)take(3670016);       // 4*896*512*2
  __bf16* Ghat4 = (__bf16*)take(3670016);
  __bf16* S3    = (__bf16*)take(81920000);      // 4*3200*3200*2
  __bf16* S4    = (__bf16*)take(6422528);       // 4*896*896*2
  float*  Zp3   = (float*) take(5017600);       // 4*98*3200*4
  float*  Zp4   = (float*) take(702464);        // 4*49*896*4
  float* invd3  = (float*)take(51200);
  float* c3     = (float*)take(51200);
  float* ksum   = (float*)take(51200);          // first 32 B used
  float* invd4  = (float*)take(14336);
  float* c4     = (float*)take(14336);

  hipMemsetAsync(divkey3, 0, zero_bytes, stream);

  norm_kernel<<<dim3(1, 100, 8), 256, 0, stream>>>(gen3, tar3, Ghat3, That3,
                                                   gen4, tar4, Ghat4, That4, ksum);
  gemm_kernel<<<2696, 256, 0, stream>>>(That3, Ghat3, S3, divkey3,
                                        That4, Ghat4, S4, divkey4);
  z_kernel<<<980, 256, 0, stream>>>(S3, divkey3, Zp3,
                                    S4, divkey4, Zp4);
  reduce_kernel<<<dim3(13, 8), 256, 0, stream>>>(Zp3, divkey3, invd3, c3,
                                                 Zp4, divkey4, invd4, c4);
  rowmax_kernel<<<588, 256, 0, stream>>>(S3, invd3, c3,
                                         S4, invd4, c4, ksum);
  final_kernel<<<1, 64, 0, stream>>>(ksum, (float*)d_out);
}

// Round 11
// 194.453 us; speedup vs baseline: 1.2739x; 1.0369x over previous
//
#include <hip/hip_runtime.h>
#include <math.h>

typedef __bf16 bf16x8 __attribute__((ext_vector_type(8)));
typedef float f32x4 __attribute__((ext_vector_type(4)));

#define EPSV 1e-5f
#define GLB(p) ((__attribute__((address_space(1))) void*)(p))
#define LDS(p) ((__attribute__((address_space(3))) void*)(p))

__device__ __forceinline__ unsigned fkey(float f) {
  unsigned b = __float_as_uint(f);
  return (b & 0x80000000u) ? ~b : (b | 0x80000000u);
}
__device__ __forceinline__ float funkey(unsigned k) {
  return __uint_as_float((k & 0x80000000u) ? (k & 0x7fffffffu) : ~k);
}

// ---- single-pass norm: block owns p-tile x all C; stats in regs+LDS, then
// apply+store bf16 [N][Ppad][C]. Pad blocks (y>=NWORK) zero the pad rows.
// Block (z=0,y=0) also zeroes ksum[8]. grid (1, 100, 8). ----
__global__ __launch_bounds__(256) void norm_kernel(
    const float* __restrict__ g3, const float* __restrict__ t3,
    __bf16* __restrict__ G3, __bf16* __restrict__ T3,
    const float* __restrict__ g4, const float* __restrict__ t4,
    __bf16* __restrict__ G4, __bf16* __restrict__ T4,
    float* __restrict__ ksum)
{
  if (blockIdx.z == 0 && blockIdx.y == 0 && threadIdx.x < 8)
    ksum[threadIdx.x] = 0.f;
  int lay = blockIdx.z >> 2, n = blockIdx.z & 3;
  const float *gen, *tar; __bf16 *Gh, *Th; int C, P, Ppad, PT, NWORK, NTOT, NG;
  if (lay == 0) { gen = g3; tar = t3; Gh = G3; Th = T3; C = 256; P = 3136; Ppad = 3200; PT = 32; NWORK = 98; NTOT = 100; NG = 8; }
  else          { gen = g4; tar = t4; Gh = G4; Th = T4; C = 512; P = 784;  Ppad = 896;  PT = 16; NWORK = 49; NTOT = 56;  NG = 16; }
  if (blockIdx.y >= (unsigned)NTOT) return;
  int pl, cg;
  if (lay == 0) { pl = threadIdx.x & 31; cg = threadIdx.x >> 5; }
  else          { pl = threadIdx.x & 15; cg = threadIdx.x >> 4; }
  int c0 = cg * 32;

  if (blockIdx.y >= (unsigned)NWORK) {  // zero pad rows
    int p = P + (blockIdx.y - NWORK) * PT + pl;
    if (p < Ppad) {
      __bf16* tp = Th + ((size_t)n * Ppad + p) * C + c0;
      __bf16* gp = Gh + ((size_t)n * Ppad + p) * C + c0;
      bf16x8 z;
      for (int j = 0; j < 8; j++) z[j] = (__bf16)0.f;
      for (int j = 0; j < 32; j += 8) { *(bf16x8*)(tp + j) = z; *(bf16x8*)(gp + j) = z; }
    }
    return;
  }

  int p = blockIdx.y * PT + pl;
  const float* tb = tar + (size_t)n * C * P + (size_t)c0 * P + p;
  const float* gb = gen + (size_t)n * C * P + (size_t)c0 * P + p;
  float tv[32], gv[32];
  float st = 0.f, sst = 0.f, sg = 0.f, ssg = 0.f;
#pragma unroll
  for (int j = 0; j < 32; j++) {
    tv[j] = tb[(size_t)j * P];
    gv[j] = gb[(size_t)j * P];
  }
#pragma unroll
  for (int j = 0; j < 32; j++) {
    st += tv[j]; sst += tv[j] * tv[j];
    sg += gv[j]; ssg += gv[j] * gv[j];
  }
  __shared__ f32x4 red[16][32];
  red[cg][pl] = f32x4{st, sst, sg, ssg};
  __syncthreads();
  for (int h = NG >> 1; h > 0; h >>= 1) {
    if (cg < h) {
      f32x4 a = red[cg][pl], b = red[cg + h][pl];
      red[cg][pl] = f32x4{a[0] + b[0], a[1] + b[1], a[2] + b[2], a[3] + b[3]};
    }
    __syncthreads();
  }
  f32x4 s = red[0][pl];
  float m = s[0] / (float)C;
  float vt = s[1] - s[0] * s[0] / (float)C;
  float vg = s[3] - 2.f * m * s[2] + (float)C * m * m;
  float it = rsqrtf(fmaxf(vt, 1e-30f));
  float ig = rsqrtf(fmaxf(vg, 1e-30f));
  __bf16* tp = Th + ((size_t)n * Ppad + p) * C + c0;
  __bf16* gp = Gh + ((size_t)n * Ppad + p) * C + c0;
#pragma unroll
  for (int j0 = 0; j0 < 32; j0 += 8) {
    bf16x8 to, go;
    for (int j = 0; j < 8; j++) {
      to[j] = (__bf16)((tv[j0 + j] - m) * it);
      go[j] = (__bf16)((gv[j0 + j] - m) * ig);
    }
    *(bf16x8*)(tp + j0) = to;
    *(bf16x8*)(gp + j0) = go;
  }
}

// ---- GEMM: exact r0 config + BALANCED XCD swizzle. r10 validated the
// mechanism (xcd = bid&7 round-robin is real: FETCH 54.9 -> 16.4 MB) but
// its naive remap dumped ALL 196 layer-4 tiles (2x MACs each) on XCD 7 ->
// 1.6x straggler, dur 49.3 -> 54.2. Fix: bijective uneven-chunk remap over
// the 2500 layer-3 blocks only (XCDs 0-3 get 313 ids, 4-7 get 312);
// layer-4 blocks stay identity (L3-resident working set, round-robin =
// balanced). Occupancy levers proven neutral; alignment load-bearing. ----
__global__ __launch_bounds__(256, 3) void gemm_kernel(
    const __bf16* __restrict__ A3, const __bf16* __restrict__ B3,
    __bf16* __restrict__ So3, unsigned* __restrict__ dk3,
    const __bf16* __restrict__ A4, const __bf16* __restrict__ B4,
    __bf16* __restrict__ So4, unsigned* __restrict__ dk4)
{
  // staging: A0 [0,8K) A1 [8K,16K) B0 [16K,24K) B1 [24K,32K)
  // epilogue reuse: 128 rows x 296 B = 37888 B
  __shared__ __attribute__((aligned(16))) char smem[37888];

  int bid = blockIdx.x;
  int id;
  if (bid < 2500) {
    int xcd = bid & 7, pos = bid >> 3;
    int off = xcd < 4 ? xcd * 313 : 1252 + (xcd - 4) * 312;
    id = off + pos;           // XCD-contiguous, balanced (313/313/313/313/312x4)
  } else {
    id = bid;                 // layer-4: identity
  }
  const __bf16 *A, *B; __bf16* S; unsigned* dk;
  int C, Ppad, Qpad, Preal, NT, n, t;
  if (id < 2500) {
    n = id / 625; t = id - n * 625;
    A = A3; B = B3; S = So3; dk = dk3; C = 256; Ppad = 3200; Qpad = 3200; Preal = 3136; NT = 25;
  } else {
    id -= 2500;
    n = id / 49; t = id - n * 49;
    A = A4; B = B4; S = So4; dk = dk4; C = 512; Ppad = 896;  Qpad = 896;  Preal = 784;  NT = 7;
  }
  // band swizzle: bands of 8 p-tiles, q fastest within a band
  int bpb = NT * 8;
  int b = t / bpb, r = t - b * bpb;
  int rem = NT - b * 8;
  int h = rem < 8 ? rem : 8;
  int pt = b * 8 + r % h, qt = r / h;
  int p0 = pt * 128, q0 = qt * 128;

  int tid = threadIdx.x;
  int w = tid >> 6, lane = tid & 63;
  int lm = lane & 15, lq = lane >> 4;
  int wrow = (w >> 1) * 64, wcol = (w & 1) * 64;

  // staging: thread tid -> row tid>>2 (and +64), chunk-slot tid&3 (16B);
  // slot s of row r holds global chunk s ^ ((r>>1)&3) (proven 0-conflict).
  int srow = tid >> 2;
  int scol = ((tid & 3) ^ ((tid >> 3) & 3)) * 8;
  const __bf16* gA = A + ((size_t)n * Ppad + p0 + srow) * C + scol;
  const __bf16* gB = B + ((size_t)n * Qpad + q0 + srow) * C + scol;
  size_t rowoff = (size_t)64 * C;

  // fragment read: row R + chunk lq -> slot lq ^ ((lm>>1)&3)
  int sl = lq ^ ((lm >> 1) & 3);
  int aoff = (wrow + lm) * 64 + sl * 16;   // + i*1024 per i-tile
  int boff = (wcol + lm) * 64 + sl * 16;

  f32x4 acc[4][4];
  for (int i = 0; i < 4; i++)
    for (int j = 0; j < 4; j++)
      acc[i][j] = f32x4{0.f, 0.f, 0.f, 0.f};

  for (int k0 = 0; k0 < C; k0 += 64) {
    __syncthreads();
#pragma unroll
    for (int sub = 0; sub < 2; sub++) {
      int kk = k0 + sub * 32;
      char* a = smem + sub * 8192 + w * 1024;
      char* bb = smem + 16384 + sub * 8192 + w * 1024;
      __builtin_amdgcn_global_load_lds(GLB(gA + kk), LDS(a), 16, 0, 0);
      __builtin_amdgcn_global_load_lds(GLB(gA + rowoff + kk), LDS(a + 4096), 16, 0, 0);
      __builtin_amdgcn_global_load_lds(GLB(gB + kk), LDS(bb), 16, 0, 0);
      __builtin_amdgcn_global_load_lds(GLB(gB + rowoff + kk), LDS(bb + 4096), 16, 0, 0);
    }
    __syncthreads();
#pragma unroll
    for (int sub = 0; sub < 2; sub++) {
      const char* ab = smem + sub * 8192;
      const char* bb = smem + 16384 + sub * 8192;
      bf16x8 af[4], bf[4];
      for (int i = 0; i < 4; i++) af[i] = *(const bf16x8*)(ab + aoff + i * 1024);
      for (int j = 0; j < 4; j++) bf[j] = *(const bf16x8*)(bb + boff + j * 1024);
      for (int i = 0; i < 4; i++)
        for (int j = 0; j < 4; j++)
          acc[i][j] = __builtin_amdgcn_mfma_f32_16x16x32_bf16(af[i], bf[j], acc[i][j], 0, 0, 0);
    }
  }

  // colmax from registers (D: row = lq*4+ri, col = lm within 16x16 sub-tile)
  float cm[4] = {-INFINITY, -INFINITY, -INFINITY, -INFINITY};
  for (int i = 0; i < 4; i++)
    for (int j = 0; j < 4; j++)
      for (int ri = 0; ri < 4; ri++) {
        int pr = p0 + wrow + i * 16 + lq * 4 + ri;
        if (pr < Preal) cm[j] = fmaxf(cm[j], (float)(__bf16)acc[i][j][ri]);
      }

  // epilogue: bounce through LDS (296-B pitch: banks = lq*8 + lm/2, conflict-
  // free), then fully-coalesced non-temporal bf16x8 row stores.
  __syncthreads();
  for (int i = 0; i < 4; i++) {
    for (int j = 0; j < 4; j++) {
      int row = wrow + i * 16 + lq * 4;
      int col = wcol + j * 16 + lm;
      for (int ri = 0; ri < 4; ri++)
        *(__bf16*)(smem + (row + ri) * 296 + col * 2) = (__bf16)acc[i][j][ri];
    }
  }
  __syncthreads();
  __bf16* Sb = S + (size_t)n * Ppad * Qpad;
  int rr = tid >> 4, cc8 = (tid & 15) * 8;
  for (int r8 = 0; r8 < 8; r8++) {
    int row = r8 * 16 + rr;
    bf16x8 v = *(const bf16x8*)(smem + row * 296 + cc8 * 2);
    __builtin_nontemporal_store(v, (bf16x8*)(Sb + (size_t)(p0 + row) * Qpad + q0 + cc8));
  }

  for (int j = 0; j < 4; j++) {
    float v = cm[j];
    v = fmaxf(v, __shfl_xor(v, 16, 64));
    v = fmaxf(v, __shfl_xor(v, 32, 64));
    if (lq == 0 && v > -INFINITY) {
      int qc = q0 + wcol + j * 16 + lm;
      atomicMax(&dk[(size_t)n * Qpad + qc], fkey(v));
    }
  }
}

// ---- z partials: block = q-tile(2048) x p-slab(32/16); NO atomics
// (r9's atomicAdd-to-Z: 43 MB HBM write, 81 us — cross-XCD fp32 atomics
// resolve at the fabric). Slab partials + reduce. exp2f-folded coefficients.
// exact 1D grid: 980 blocks ----
__global__ __launch_bounds__(256) void z_kernel(
    const __bf16* __restrict__ S3, const unsigned* __restrict__ dk3, float* __restrict__ Zp3,
    const __bf16* __restrict__ S4, const unsigned* __restrict__ dk4, float* __restrict__ Zp4)
{
  int id = blockIdx.x;
  const __bf16* S; const unsigned* dk; float* Zp;
  int Ppad, Qreal, Qpad, NSL, SLAB, n, qx, sy;
  if (id < 784) {
    n = id / 196; int r = id - n * 196; sy = r >> 1; qx = r & 1;
    S = S3; dk = dk3; Zp = Zp3; Ppad = 3200; Qreal = 3136; Qpad = 3200; NSL = 98; SLAB = 32;
  } else {
    id -= 784;
    n = id / 49; sy = id - n * 49; qx = 0;
    S = S4; dk = dk4; Zp = Zp4; Ppad = 896;  Qreal = 784;  Qpad = 896;  NSL = 49; SLAB = 16;
  }
  int q = (qx * 256 + threadIdx.x) * 8;
  if (q >= Qreal) return;
  float idv2[8], nid2[8];
  const unsigned* dkp = dk + (size_t)n * Qpad + q;
#pragma unroll
  for (int j = 0; j < 8; j++) {
    float mx = funkey(dkp[j]);
    float d = 0.5f * (1.f - mx) + EPSV;
    float iv = 1.4426950408889634f / d;   // log2(e)/d
    idv2[j] = iv;
    nid2[j] = -iv;
  }
  int p0 = sy * SLAB;
  const __bf16* Sp = S + (size_t)n * Ppad * Qpad + q;
  float acc[8] = {0.f, 0.f, 0.f, 0.f, 0.f, 0.f, 0.f, 0.f};
  for (int pb = 0; pb < SLAB; pb += 8) {
    bf16x8 sv[8];
#pragma unroll
    for (int r = 0; r < 8; r++)
      sv[r] = *(const bf16x8*)(Sp + (size_t)(p0 + pb + r) * Qpad);
#pragma unroll
    for (int r = 0; r < 8; r++)
      for (int j = 0; j < 8; j++)
        acc[j] += exp2f(fmaf((float)sv[r][j], idv2[j], nid2[j]));
  }
  float* zp = Zp + ((size_t)n * NSL + sy) * Qpad + q;
  *(f32x4*)zp = f32x4{acc[0], acc[1], acc[2], acc[3]};
  *(f32x4*)(zp + 4) = f32x4{acc[4], acc[5], acc[6], acc[7]};
}

// ---- reduce: Z[q] = sum_slab Zp ; invd[q] ; c[q] = -log(Z)-invd ---- grid (13,8)
__global__ __launch_bounds__(256) void reduce_kernel(
    const float* __restrict__ Zp3, const unsigned* __restrict__ dk3,
    float* __restrict__ invd3, float* __restrict__ c3,
    const float* __restrict__ Zp4, const unsigned* __restrict__ dk4,
    float* __restrict__ invd4, float* __restrict__ c4)
{
  int lay = blockIdx.y >> 2, n = blockIdx.y & 3;
  const float* Zp; const unsigned* dk; float *invd, *c; int Qreal, Qpad, NSL;
  if (lay == 0) { Zp = Zp3; dk = dk3; invd = invd3; c = c3; Qreal = 3136; Qpad = 3200; NSL = 98; }
  else          { Zp = Zp4; dk = dk4; invd = invd4; c = c4; Qreal = 784;  Qpad = 896;  NSL = 49; }
  int q = blockIdx.x * 256 + threadIdx.x;
  if (q >= Qreal) return;
  float s0 = 0.f, s1 = 0.f, s2 = 0.f, s3 = 0.f;
  int sl = 0;
  for (; sl + 4 <= NSL; sl += 4) {
    s0 += Zp[((size_t)n * NSL + sl) * Qpad + q];
    s1 += Zp[((size_t)n * NSL + sl + 1) * Qpad + q];
    s2 += Zp[((size_t)n * NSL + sl + 2) * Qpad + q];
    s3 += Zp[((size_t)n * NSL + sl + 3) * Qpad + q];
  }
  for (; sl < NSL; sl++) s0 += Zp[((size_t)n * NSL + sl) * Qpad + q];
  float s = (s0 + s1) + (s2 + s3);
  float mx = funkey(dk[(size_t)n * Qpad + q]);
  float d = 0.5f * (1.f - mx) + EPSV;
  float idv = 1.f / d;
  invd[(size_t)n * Qpad + q] = idv;
  c[(size_t)n * Qpad + q] = -logf(s) - idv;
}

// ---- rowmax: per-block max_q (S*invd + c) over ROWS rows, exp'd + summed,
// one atomicAdd into ksum[lay*4+n]. ROWS=32 (L3) / 16 (L4): 588 blocks. ----
template<int ROWS>
__device__ __forceinline__ float rowmax_partial(
    const __bf16* __restrict__ Sp, const float* __restrict__ idp,
    const float* __restrict__ cp, int nq8, int Qpad)
{
  float m[ROWS];
#pragma unroll
  for (int r = 0; r < ROWS; r++) m[r] = -INFINITY;
  for (int i = threadIdx.x; i < nq8; i += 256) {
    f32x4 i0 = *(const f32x4*)(idp + (size_t)i * 8);
    f32x4 i1 = *(const f32x4*)(idp + (size_t)i * 8 + 4);
    f32x4 c0 = *(const f32x4*)(cp + (size_t)i * 8);
    f32x4 c1 = *(const f32x4*)(cp + (size_t)i * 8 + 4);
#pragma unroll
    for (int r = 0; r < ROWS; r++) {
      bf16x8 sv = *(const bf16x8*)(Sp + (size_t)r * Qpad + (size_t)i * 8);
#pragma unroll
      for (int j = 0; j < 4; j++)
        m[r] = fmaxf(m[r], fmaf((float)sv[j], i0[j], c0[j]));
#pragma unroll
      for (int j = 0; j < 4; j++)
        m[r] = fmaxf(m[r], fmaf((float)sv[j + 4], i1[j], c1[j]));
    }
  }
#pragma unroll
  for (int r = 0; r < ROWS; r++)
    for (int off = 32; off > 0; off >>= 1)
      m[r] = fmaxf(m[r], __shfl_xor(m[r], off, 64));
  __shared__ float red[4][ROWS];
  int w = threadIdx.x >> 6;
  if ((threadIdx.x & 63) == 0)
#pragma unroll
    for (int r = 0; r < ROWS; r++) red[w][r] = m[r];
  __syncthreads();
  float e = 0.f;
  if (threadIdx.x < ROWS) {
    int r = threadIdx.x;
    float mr = fmaxf(fmaxf(red[0][r], red[1][r]), fmaxf(red[2][r], red[3][r]));
    e = __expf(mr);
  }
  if (threadIdx.x < 64) {
#pragma unroll
    for (int off = 1; off < ROWS; off <<= 1)
      e += __shfl_xor(e, off, 64);
  }
  return e;  // valid in lane 0
}

__global__ __launch_bounds__(256) void rowmax_kernel(
    const __bf16* __restrict__ S3, const float* __restrict__ invd3,
    const float* __restrict__ c3,
    const __bf16* __restrict__ S4, const float* __restrict__ invd4,
    const float* __restrict__ c4, float* __restrict__ ksum)
{
  int id = blockIdx.x;
  if (id < 392) {
    int n = id / 98, blk = id - n * 98;
    const __bf16* Sp = S3 + ((size_t)n * 3200 + blk * 32) * 3200;
    float e = rowmax_partial<32>(Sp, invd3 + (size_t)n * 3200,
                                 c3 + (size_t)n * 3200, 392, 3200);
    if (threadIdx.x == 0) atomicAdd(&ksum[n], e);
  } else {
    id -= 392;
    int n = id / 49, blk = id - n * 49;
    const __bf16* Sp = S4 + ((size_t)n * 896 + blk * 16) * 896;
    float e = rowmax_partial<16>(Sp, invd4 + (size_t)n * 896,
                                 c4 + (size_t)n * 896, 98, 896);
    if (threadIdx.x == 0) atomicAdd(&ksum[4 + n], e);
  }
}

// loss = 0.5 * sum_n -log(ksum3/P3) + 1.0 * sum_n -log(ksum4/P4)
__global__ void final_kernel(const float* __restrict__ ksum, float* __restrict__ out)
{
  if (threadIdx.x == 0) {
    float lp3 = logf(3136.f), lp4 = logf(784.f);
    float total = 0.f;
    for (int n = 0; n < 4; n++) total += 0.5f * (lp3 - logf(ksum[n]));
    for (int n = 0; n < 4; n++) total += 1.0f * (lp4 - logf(ksum[4 + n]));
    out[0] = total;
  }
}

extern "C" void kernel_launch(void* const* d_in, const int* in_sizes, int n_in,
                              void* d_out, int out_size, void* d_ws, size_t ws_size,
                              hipStream_t stream)
{
  const float* gen3 = (const float*)d_in[0];
  const float* tar3 = (const float*)d_in[1];
  const float* gen4 = (const float*)d_in[2];
  const float* tar4 = (const float*)d_in[3];

  char* ws = (char*)d_ws;
  size_t off = 0;
  auto take = [&](size_t bytes) { char* p = ws + off; off += bytes; return p; };

  // ---- workspace layout: byte-identical to r7's proven 195.3-us layout.
  // DO NOT insert allocations before the big buffers (32-B shift = +28%
  // GEMM, r1/r2). ----
  unsigned* divkey3 = (unsigned*)take(51200);   // 4*3200*4
  unsigned* divkey4 = (unsigned*)take(14336);   // 4*896*4
  size_t zero_bytes = off;                      // = 65536
  __bf16* That3 = (__bf16*)take(6553600);       // 4*3200*256*2   @ 65536
  __bf16* Ghat3 = (__bf16*)take(6553600);
  __bf16* That4 = (__bf16*)take(3670016);       // 4*896*512*2
  __bf16* Ghat4 = (__bf16*)take(3670016);
  __bf16* S3    = (__bf16*)take(81920000);      // 4*3200*3200*2
  __bf16* S4    = (__bf16*)take(6422528);       // 4*896*896*2
  float*  Zp3   = (float*) take(5017600);       // 4*98*3200*4
  float*  Zp4   = (float*) take(702464);        // 4*49*896*4
  float* invd3  = (float*)take(51200);
  float* c3     = (float*)take(51200);
  float* ksum   = (float*)take(51200);          // first 32 B used
  float* invd4  = (float*)take(14336);
  float* c4     = (float*)take(14336);

  hipMemsetAsync(divkey3, 0, zero_bytes, stream);

  norm_kernel<<<dim3(1, 100, 8), 256, 0, stream>>>(gen3, tar3, Ghat3, That3,
                                                   gen4, tar4, Ghat4, That4, ksum);
  gemm_kernel<<<2696, 256, 0, stream>>>(That3, Ghat3, S3, divkey3,
                                        That4, Ghat4, S4, divkey4);
  z_kernel<<<980, 256, 0, stream>>>(S3, divkey3, Zp3,
                                    S4, divkey4, Zp4);
  reduce_kernel<<<dim3(13, 8), 256, 0, stream>>>(Zp3, divkey3, invd3, c3,
                                                 Zp4, divkey4, invd4, c4);
  rowmax_kernel<<<588, 256, 0, stream>>>(S3, invd3, c3,
                                         S4, invd4, c4, ksum);
  final_kernel<<<1, 64, 0, stream>>>(ksum, (float*)d_out);
}